// Round 3
// baseline (187.098 us; speedup 1.0000x reference)
//
#include <hip/hip_runtime.h>
#include <math.h>

#define B_  16
#define N_  8192
#define D_  128
#define H_  64
#define E_  64
#define EPSLN 1e-5f
#define NBLK 256u   // grid = 256 blocks; capacity 2/CU x 256 CU = 512 -> 2x residency margin

typedef __attribute__((ext_vector_type(8))) short short8;
typedef __attribute__((ext_vector_type(4))) float f32x4;

// workspace layout (bytes):
//   partial : B*16*D floats    @ 0        (131072)  per-block colacc partials
//   Mt      : B*E*D bf16       @ 131072   (262144)  Mt[b][e][d]
//   Tg      : B*E floats       @ 393216
//   Cg      : B*E floats       @ 397312
//   bar     : 2 uints          @ 401408   (memset each launch)
//   xb      : 256 blk * 64 KB  @ 409600   (16 MB, swizzled bf16 tile-B dumps)
#define WSB_PART 0
#define WSB_MT   131072
#define WSB_T    393216
#define WSB_C    397312
#define WSB_BAR  401408
#define WSB_XB   409600

static __device__ __forceinline__ unsigned short f2bf(float f) {
    union { float f; unsigned u; } c; c.f = f;
    unsigned u = c.u;
    return (unsigned short)((u + 0x7FFFu + ((u >> 16) & 1u)) >> 16);  // RNE
}
static __device__ __forceinline__ float bf2f(short s) {
    union { unsigned u; float f; } c;
    c.u = ((unsigned)(unsigned short)s) << 16;
    return c.f;
}

// Grid barrier. 2x residency margin makes starvation essentially impossible;
// bounded spin (2^15 polls x s_sleep(32) ~ 33 ms) turns any pathological case
// into a fast wrong answer instead of a watchdog kill.
static __device__ __forceinline__ void gridbar(unsigned* bar, unsigned target) {
    __syncthreads();
    if (threadIdx.x == 0) {
        __threadfence();
        atomicAdd(bar, 1u);
        int spins = 0;
        while (atomicAdd(bar, 0u) < target) {
            __builtin_amdgcn_s_sleep(32);
            if (++spins > (1 << 15)) break;
        }
        __threadfence();
    }
    __syncthreads();
}

// ---- round-0 verified staging: thread t owns row t (fp32 -> swizzled bf16 LDS,
//      serial stats in registers, no shuffles) -------------------------------
static __device__ __forceinline__ void stage_rows(const float* __restrict__ xrows,
                                                  int t, short* xs,
                                                  float* muA, float* rsA) {
    const float4* xrow = (const float4*)(xrows + (size_t)t * D_);
    float s = 0.f, s2 = 0.f;
    int sw = t & 15;
#pragma unroll
    for (int g = 0; g < 16; ++g) {            // 16B granule = 8 bf16
        float4 va = xrow[2 * g], vb = xrow[2 * g + 1];
        s  += (va.x + va.y) + (va.z + va.w) + (vb.x + vb.y) + (vb.z + vb.w);
        s2 += (va.x * va.x + va.y * va.y) + (va.z * va.z + va.w * va.w)
            + (vb.x * vb.x + vb.y * vb.y) + (vb.z * vb.z + vb.w * vb.w);
        short8 sv;
        sv[0] = (short)f2bf(va.x); sv[1] = (short)f2bf(va.y);
        sv[2] = (short)f2bf(va.z); sv[3] = (short)f2bf(va.w);
        sv[4] = (short)f2bf(vb.x); sv[5] = (short)f2bf(vb.y);
        sv[6] = (short)f2bf(vb.z); sv[7] = (short)f2bf(vb.w);
        *(short8*)&xs[t * 128 + ((g ^ sw) * 8)] = sv;
    }
    float mu  = s * (1.f / D_);
    float var = s2 * (1.f / D_) - mu * mu;
    muA[t] = mu;
    rsA[t] = rsqrtf(var + EPSLN);
}

// ---- colsum: thread (rc = t>>4, cg = t&15) owns cols cg*8..+7 over rows
//      rc*16..+15; ca[j] += rs*x, srm += rs*mu (column-independent term) -----
static __device__ __forceinline__ void colsum_pass(const short* xs,
                                                   const float* muA, const float* rsA,
                                                   int t, float* ca, float* srm) {
    int rc = t >> 4, cg = t & 15;
#pragma unroll
    for (int i = 0; i < 16; ++i) {
        int r = rc * 16 + i;
        float rs = rsA[r];
        *srm += rs * muA[r];
        short8 v = *(const short8*)&xs[r * 128 + ((cg ^ (r & 15)) << 3)];
        ca[0] += rs * bf2f(v[0]); ca[1] += rs * bf2f(v[1]);
        ca[2] += rs * bf2f(v[2]); ca[3] += rs * bf2f(v[3]);
        ca[4] += rs * bf2f(v[4]); ca[5] += rs * bf2f(v[5]);
        ca[6] += rs * bf2f(v[6]); ca[7] += rs * bf2f(v[7]);
    }
}

// ---- round-0 verified MFMA main + epilogue for one 256-row LDS-resident tile
static __device__ __forceinline__ void mfma_tile(const short* xs,
                                                 const unsigned short* __restrict__ Mb,
                                                 const float* muA, const float* rsA,
                                                 const float* Tl, const float* Cl,
                                                 float* __restrict__ outp,
                                                 int wv, int lane) {
    int m16 = lane & 15, quad = lane >> 4;

    f32x4 acc[4][4];
#pragma unroll
    for (int i = 0; i < 4; ++i)
#pragma unroll
        for (int j = 0; j < 4; ++j) acc[i][j] = (f32x4){0.f, 0.f, 0.f, 0.f};

#pragma unroll
    for (int kc = 0; kc < 4; ++kc) {
        short8 af[4], bf[4];
#pragma unroll
        for (int mt = 0; mt < 4; ++mt) {
            int row = wv * 64 + mt * 16 + m16;
            int g = kc * 4 + quad;
            af[mt] = *(const short8*)&xs[row * 128 + ((g ^ m16) * 8)];
        }
#pragma unroll
        for (int nt = 0; nt < 4; ++nt) {
            bf[nt] = *(const short8*)(Mb + (size_t)(nt * 16 + m16) * D_ + kc * 32 + quad * 8);
        }
#pragma unroll
        for (int mt = 0; mt < 4; ++mt)
#pragma unroll
            for (int nt = 0; nt < 4; ++nt)
                acc[mt][nt] = __builtin_amdgcn_mfma_f32_16x16x32_bf16(
                    af[mt], bf[nt], acc[mt][nt], 0, 0, 0);
    }

#pragma unroll
    for (int mt = 0; mt < 4; ++mt) {
        int rb = wv * 64 + mt * 16 + quad * 4;
        float mu0 = muA[rb + 0], rs0 = rsA[rb + 0];
        float mu1 = muA[rb + 1], rs1 = rsA[rb + 1];
        float mu2 = muA[rb + 2], rs2 = rsA[rb + 2];
        float mu3 = muA[rb + 3], rs3 = rsA[rb + 3];
#pragma unroll
        for (int nt = 0; nt < 4; ++nt) {
            int col = nt * 16 + m16;
            float Tc = Tl[col], Cc = Cl[col];
            float* o = outp + (size_t)rb * E_ + col;
            o[0 * E_] = rs0 * (acc[mt][nt][0] - mu0 * Tc) + Cc;
            o[1 * E_] = rs1 * (acc[mt][nt][1] - mu1 * Tc) + Cc;
            o[2 * E_] = rs2 * (acc[mt][nt][2] - mu2 * Tc) + Cc;
            o[3 * E_] = rs3 * (acc[mt][nt][3] - mu3 * Tc) + Cc;
        }
    }
}

// ---------------------------------------------------------------------------
// Fused kernel. Grid (16,16) = 256 blocks, 256 thr, 512 rows/block.
// Phase 1: tile B (rows 256..511) stage->stats->colsum in LDS, dump to ws;
//          tile A (rows 0..255) stage->stats->colsum, STAYS LDS-resident.
//          colacc partials -> ws.
// bar0. Phase 2 (bx<4): combine -> Mt/Tg/Cg.  bar1.
// Phase 3a: MFMA tile A (resident). Phase 3b: reload tile B, MFMA.
// x read from HBM exactly once.
// ---------------------------------------------------------------------------
__global__ __launch_bounds__(256, 2) void k_fused(
    const float* __restrict__ x,
    const float* __restrict__ ln_w, const float* __restrict__ ln_b,
    const float* __restrict__ Wl,   const float* __restrict__ bl,
    const float* __restrict__ Wr,   const float* __restrict__ br,
    const float* __restrict__ Wo,   const float* __restrict__ bo,
    float* __restrict__ partial, unsigned short* __restrict__ Mt,
    float* __restrict__ Tg, float* __restrict__ Cg,
    unsigned* __restrict__ bar, unsigned short* __restrict__ xb,
    float* __restrict__ out)
{
    __shared__ short xs[256 * 128];          // 64 KB bf16, swizzled granules
    __shared__ float muA[256], rsA[256], muB[256], rsB[256];
    __shared__ float red[16 * 128];          // 8 KB colsum partials
    __shared__ float cm[D_], mlv[H_], uu[H_], qq[H_];
    __shared__ float Tl[E_], Cl[E_];

    int by = blockIdx.y, bx = blockIdx.x, t = threadIdx.x;
    int rowbase = bx * 512;
    const float* xrows = x + (size_t)(by * N_ + rowbase) * D_;
    unsigned short* xbB = xb + (size_t)(by * 16 + bx) * (256 * 128);

    float ca[8] = {0.f, 0.f, 0.f, 0.f, 0.f, 0.f, 0.f, 0.f};
    float srm = 0.f;

    // ---- phase 1: tile B first ---------------------------------------------
    stage_rows(xrows + (size_t)256 * D_, t, xs, muB, rsB);
    __syncthreads();
    colsum_pass(xs, muB, rsB, t, ca, &srm);
    {   // linear dump of the (already swizzled) tile to ws — fully coalesced
        const short8* s8 = (const short8*)xs;
        short8* d8 = (short8*)xbB;
#pragma unroll
        for (int i = 0; i < 16; ++i) d8[t + 256 * i] = s8[t + 256 * i];
    }
    __syncthreads();                         // all xs reads done before overwrite

    // ---- tile A: stays resident --------------------------------------------
    stage_rows(xrows, t, xs, muA, rsA);
    __syncthreads();
    colsum_pass(xs, muA, rsA, t, ca, &srm);

    {   // per-thread col values -> LDS -> per-block partial
        int rc = t >> 4, cg = t & 15;
#pragma unroll
        for (int j = 0; j < 8; ++j) red[rc * 128 + cg * 8 + j] = ca[j] - srm;
    }
    __syncthreads();
    if (t < 128) {
        float v = 0.f;
#pragma unroll
        for (int rc = 0; rc < 16; ++rc) v += red[rc * 128 + t];
        partial[(size_t)(by * 16 + bx) * D_ + t] = v;
    }

    gridbar(&bar[0], NBLK);

    // ---- phase 2: combine (4 blocks per batch) -----------------------------
    if (bx < 4) {
        if (t < D_) {
            float sacc = 0.f;
#pragma unroll
            for (int j = 0; j < 16; ++j)
                sacc += partial[(size_t)(by * 16 + j) * D_ + t];
            cm[t] = ln_w[t] * sacc * (1.f / N_) + ln_b[t];
        }
        __syncthreads();
        if (t < H_) {
            float a = bl[t], u = 0.f, q = 0.f;
            for (int d = 0; d < D_; ++d) {
                float wr = Wr[d * H_ + t];
                a += cm[d] * Wl[d * H_ + t];
                u += ln_w[d] * wr;
                q += ln_b[d] * wr;
            }
            mlv[t] = a; uu[t] = u; qq[t] = q + br[t];
        }
        __syncthreads();
        {
            int d  = bx * 32 + (t >> 3);
            int eo = (t & 7) * 8;
            float a0 = 0, a1 = 0, a2 = 0, a3 = 0, a4 = 0, a5 = 0, a6 = 0, a7 = 0;
            for (int h = 0; h < H_; ++h) {
                float coef = Wr[d * H_ + h] * mlv[h];   // P folded into the loop
                const float4* wo4 = (const float4*)&Wo[h * E_ + eo];
                float4 pa = wo4[0], pb = wo4[1];
                a0 += coef * pa.x; a1 += coef * pa.y; a2 += coef * pa.z; a3 += coef * pa.w;
                a4 += coef * pb.x; a5 += coef * pb.y; a6 += coef * pb.z; a7 += coef * pb.w;
            }
            float wd = ln_w[d];
            size_t mb = (size_t)by * E_ * D_;
            Mt[mb + (size_t)(eo + 0) * D_ + d] = f2bf(wd * a0);
            Mt[mb + (size_t)(eo + 1) * D_ + d] = f2bf(wd * a1);
            Mt[mb + (size_t)(eo + 2) * D_ + d] = f2bf(wd * a2);
            Mt[mb + (size_t)(eo + 3) * D_ + d] = f2bf(wd * a3);
            Mt[mb + (size_t)(eo + 4) * D_ + d] = f2bf(wd * a4);
            Mt[mb + (size_t)(eo + 5) * D_ + d] = f2bf(wd * a5);
            Mt[mb + (size_t)(eo + 6) * D_ + d] = f2bf(wd * a6);
            Mt[mb + (size_t)(eo + 7) * D_ + d] = f2bf(wd * a7);
        }
        if (bx == 0 && t < E_) {
            float T = 0.f, C = bo[t];
            for (int h = 0; h < H_; ++h) {
                float p = mlv[h] * Wo[h * E_ + t];
                T += uu[h] * p;
                C += qq[h] * p;
            }
            Tg[by * E_ + t] = T;
            Cg[by * E_ + t] = C;
        }
    }

    gridbar(&bar[1], NBLK);

    // ---- phase 3 ------------------------------------------------------------
    if (t < E_) { Tl[t] = Tg[by * E_ + t]; Cl[t] = Cg[by * E_ + t]; }
    __syncthreads();

    int wv = t >> 6, lane = t & 63;
    const unsigned short* Mb = Mt + (size_t)by * E_ * D_;
    size_t ob = (size_t)(by * N_ + rowbase) * E_;

    mfma_tile(xs, Mb, muA, rsA, Tl, Cl, out + ob, wv, lane);     // tile A

    __syncthreads();                         // MFMA reads of xs complete
    {   // reload tile B (linear, coalesced)
        const short8* s8 = (const short8*)xbB;
        short8* d8 = (short8*)xs;
#pragma unroll
        for (int i = 0; i < 16; ++i) d8[t + 256 * i] = s8[t + 256 * i];
    }
    __syncthreads();

    mfma_tile(xs, Mb, muB, rsB, Tl, Cl, out + ob + (size_t)256 * E_, wv, lane);
}

extern "C" void kernel_launch(void* const* d_in, const int* in_sizes, int n_in,
                              void* d_out, int out_size, void* d_ws, size_t ws_size,
                              hipStream_t stream) {
    const float* x    = (const float*)d_in[0];
    const float* ln_w = (const float*)d_in[1];
    const float* ln_b = (const float*)d_in[2];
    const float* Wl   = (const float*)d_in[3];
    const float* bl   = (const float*)d_in[4];
    const float* Wr   = (const float*)d_in[5];
    const float* br   = (const float*)d_in[6];
    const float* Wo   = (const float*)d_in[7];
    const float* bo   = (const float*)d_in[8];
    float* out = (float*)d_out;
    char* ws   = (char*)d_ws;

    float*          partial = (float*)(ws + WSB_PART);
    unsigned short* Mt      = (unsigned short*)(ws + WSB_MT);
    float*          Tg      = (float*)(ws + WSB_T);
    float*          Cg      = (float*)(ws + WSB_C);
    unsigned*       bar     = (unsigned*)(ws + WSB_BAR);
    unsigned short* xb      = (unsigned short*)(ws + WSB_XB);

    hipMemsetAsync(bar, 0, 2 * sizeof(unsigned), stream);

    k_fused<<<dim3(16, 16), dim3(256), 0, stream>>>(
        x, ln_w, ln_b, Wl, bl, Wr, br, Wo, bo,
        partial, Mt, Tg, Cg, bar, xb, out);
}